// Round 2
// baseline (343.606 us; speedup 1.0000x reference)
//
#include <hip/hip_runtime.h>
#include <cstddef>

#define NEDGES   800000
#define NRAD     32
#define MAXZ     100
#define T1_OFF   0
#define T2_OFF   (MAXZ * 128)
#define WC_OFF   (2 * MAXZ * 128)

// ---------------------------------------------------------------------------
// Prep: fold the three weight blocks into small tables.
//   blocks 0..99   : T1[z][d] = b[d] + sum_k embed_w[z][k]*w_edge[k][d]
//                    T2[z][d] =        sum_k embed_w[z][k]*w_edge[128+k][d]
//   blocks 100..131: Wc[q][d] =        sum_m w_rbf[q][m]*w_edge[256+m][d]
// ---------------------------------------------------------------------------
__global__ __launch_bounds__(128)
void prep_kernel(const float* __restrict__ embed_w,
                 const float* __restrict__ w_rbf,
                 const float* __restrict__ w_edge,
                 const float* __restrict__ b_edge,
                 float* __restrict__ ws) {
    const int d = threadIdx.x;
    const int b = blockIdx.x;
    if (b < MAXZ) {
        float a1 = b_edge[d];
        float a2 = 0.f;
        #pragma unroll 8
        for (int k = 0; k < 128; ++k) {
            const float e = embed_w[b * 128 + k];
            a1 = fmaf(e, w_edge[k * 128 + d], a1);
            a2 = fmaf(e, w_edge[(128 + k) * 128 + d], a2);
        }
        ws[T1_OFF + b * 128 + d] = a1;
        ws[T2_OFF + b * 128 + d] = a2;
    } else {
        const int q = b - MAXZ;
        float a = 0.f;
        #pragma unroll 8
        for (int m = 0; m < 128; ++m)
            a = fmaf(w_rbf[q * 128 + m], w_edge[(256 + m) * 128 + d], a);
        ws[WC_OFF + q * 128 + d] = a;
    }
}

// ---------------------------------------------------------------------------
// Main: one EDGE PAIR per wave per iteration; 2 columns per lane.
//   - Wc[:, 2l:2l+2] register-resident (64 VGPRs), loaded once.
//   - edge index wave-uniform -> idx/x/rbf loads scalarize to s_load
//     (rbf row lands in SGPRs; v_fmac uses the SGPR operand).
//   - zero LDS.
// ---------------------------------------------------------------------------
__global__ __launch_bounds__(256)
void edge_kernel(const int* __restrict__ x,
                 const float* __restrict__ rbf,
                 const int* __restrict__ idx_i,
                 const int* __restrict__ idx_j,
                 const float* __restrict__ ws,
                 float* __restrict__ out) {
    const int lane = threadIdx.x & 63;
    const int wid  = __builtin_amdgcn_readfirstlane(threadIdx.x >> 6);  // 0..3
    const int gw   = blockIdx.x * 4 + wid;
    const int nw   = gridDim.x * 4;

    const float* __restrict__ T1 = ws + T1_OFF;
    const float* __restrict__ T2 = ws + T2_OFF;

    // Per-lane slice of Wc: columns 2*lane, 2*lane+1 for all 32 q. 64 VGPRs.
    float2 wc[NRAD];
    #pragma unroll
    for (int q = 0; q < NRAD; ++q)
        wc[q] = *(const float2*)(ws + WC_OFF + q * 128 + 2 * lane);

    const int col = 2 * lane;

    for (int p = gw; p < NEDGES / 2; p += nw) {
        const int pu = __builtin_amdgcn_readfirstlane(p);   // force uniform
        const int e0 = 2 * pu;
        const int e1 = e0 + 1;

        // wave-uniform scalar chain: idx -> z -> table row base
        const int zj0 = x[idx_j[e0]];
        const int zi0 = x[idx_i[e0]];
        const int zj1 = x[idx_j[e1]];
        const int zi1 = x[idx_i[e1]];

        const float* __restrict__ r0 = rbf + (size_t)e0 * NRAD;
        const float* __restrict__ r1 = rbf + (size_t)e1 * NRAD;

        float2 a0 = *(const float2*)(T1 + zj0 * 128 + col);
        float2 t0 = *(const float2*)(T2 + zi0 * 128 + col);
        float2 a1 = *(const float2*)(T1 + zj1 * 128 + col);
        float2 t1 = *(const float2*)(T2 + zi1 * 128 + col);
        a0.x += t0.x; a0.y += t0.y;
        a1.x += t1.x; a1.y += t1.y;

        #pragma unroll
        for (int q = 0; q < NRAD; ++q) {
            const float s0 = r0[q];    // uniform address -> SGPR operand
            const float s1 = r1[q];
            a0.x = fmaf(s0, wc[q].x, a0.x);
            a0.y = fmaf(s0, wc[q].y, a0.y);
            a1.x = fmaf(s1, wc[q].x, a1.x);
            a1.y = fmaf(s1, wc[q].y, a1.y);
        }

        float2 o0, o1;
        o0.x = a0.x / (1.f + __expf(-a0.x));
        o0.y = a0.y / (1.f + __expf(-a0.y));
        o1.x = a1.x / (1.f + __expf(-a1.x));
        o1.y = a1.y / (1.f + __expf(-a1.y));

        *(float2*)(out + (size_t)e0 * 128 + col) = o0;
        *(float2*)(out + (size_t)e1 * 128 + col) = o1;
    }
}

extern "C" void kernel_launch(void* const* d_in, const int* in_sizes, int n_in,
                              void* d_out, int out_size, void* d_ws, size_t ws_size,
                              hipStream_t stream) {
    const int*   x       = (const int*)d_in[0];
    const float* rbf     = (const float*)d_in[1];
    const int*   idx_i   = (const int*)d_in[2];
    const int*   idx_j   = (const int*)d_in[3];
    const float* embed_w = (const float*)d_in[4];
    const float* w_rbf   = (const float*)d_in[5];
    const float* w_edge  = (const float*)d_in[6];
    const float* b_edge  = (const float*)d_in[7];
    float* out = (float*)d_out;
    float* ws  = (float*)d_ws;

    prep_kernel<<<MAXZ + NRAD, 128, 0, stream>>>(embed_w, w_rbf, w_edge, b_edge, ws);
    edge_kernel<<<2048, 256, 0, stream>>>(x, rbf, idx_i, idx_j, ws, out);
}

// Round 3
// 314.259 us; speedup vs baseline: 1.0934x; 1.0934x over previous
//
#include <hip/hip_runtime.h>
#include <cstddef>

#define NEDGES   800000
#define NRAD     32
#define MAXZ     100
#define T1_OFF   0
#define T2_OFF   (MAXZ * 128)            // 12800
#define WC_OFF   (2 * MAXZ * 128)        // 25600
#define ZP_OFF   (2 * MAXZ * 128 + NRAD * 128)   // 29696 floats in

// ---------------------------------------------------------------------------
// Prep A: fold weights into tables.
//   T1[z][d] = b[d] + embed_w[z]·w_edge[0:128, d]
//   T2[z][d] =        embed_w[z]·w_edge[128:256, d]
//   Wc[q][d] =        w_rbf[q]·w_edge[256:384, d]
// ---------------------------------------------------------------------------
__global__ __launch_bounds__(128)
void prep_kernel(const float* __restrict__ embed_w,
                 const float* __restrict__ w_rbf,
                 const float* __restrict__ w_edge,
                 const float* __restrict__ b_edge,
                 float* __restrict__ ws) {
    const int d = threadIdx.x;
    const int b = blockIdx.x;
    if (b < MAXZ) {
        float a1 = b_edge[d];
        float a2 = 0.f;
        #pragma unroll 8
        for (int k = 0; k < 128; ++k) {
            const float e = embed_w[b * 128 + k];
            a1 = fmaf(e, w_edge[k * 128 + d], a1);
            a2 = fmaf(e, w_edge[(128 + k) * 128 + d], a2);
        }
        ws[T1_OFF + b * 128 + d] = a1;
        ws[T2_OFF + b * 128 + d] = a2;
    } else {
        const int q = b - MAXZ;
        float a = 0.f;
        #pragma unroll 8
        for (int m = 0; m < 128; ++m)
            a = fmaf(w_rbf[q * 128 + m], w_edge[(256 + m) * 128 + d], a);
        ws[WC_OFF + q * 128 + d] = a;
    }
}

// ---------------------------------------------------------------------------
// Prep B: zp[e] = (x[idx_j[e]] << 8) | x[idx_i[e]]  — removes one dependent
// load level from the hot loop (zp -> T instead of idx -> x -> T).
// 3125 blocks x 256 = exactly 800000 threads.
// ---------------------------------------------------------------------------
__global__ __launch_bounds__(256)
void zp_kernel(const int* __restrict__ x,
               const int* __restrict__ idx_i,
               const int* __restrict__ idx_j,
               int* __restrict__ zp) {
    const int e = blockIdx.x * 256 + threadIdx.x;
    zp[e] = (x[idx_j[e]] << 8) | x[idx_i[e]];
}

// ---------------------------------------------------------------------------
// Main: one edge PAIR per wave per iteration; 2 columns per lane.
//   - Wc[:, 2l:2l+2] register-resident: 64 VGPRs. __launch_bounds__(256,4)
//     gives the allocator a 128-VGPR budget so it is NOT rematerialized
//     (R2 failure mode: 48 VGPRs -> Wc reloaded from global every iter).
//   - zp/rbf addresses wave-uniform -> scalar loads (s_load_dwordx16 for
//     rbf rows); FMAs consume the SGPR operand. Zero LDS.
// ---------------------------------------------------------------------------
__global__ __launch_bounds__(256, 4)
void edge_kernel(const float* __restrict__ rbf,
                 const int* __restrict__ zp,
                 const float* __restrict__ ws,
                 float* __restrict__ out) {
    const int lane = threadIdx.x & 63;
    const int wid  = threadIdx.x >> 6;
    const int nw   = gridDim.x * 4;
    const int gw   = __builtin_amdgcn_readfirstlane(blockIdx.x * 4 + wid);

    const float* __restrict__ T1 = ws + T1_OFF;
    const float* __restrict__ T2 = ws + T2_OFF;

    float2 wc[NRAD];                       // 64 VGPRs, loaded once
    #pragma unroll
    for (int q = 0; q < NRAD; ++q)
        wc[q] = *(const float2*)(ws + WC_OFF + q * 128 + 2 * lane);

    const int col = 2 * lane;

    for (int p = gw; p < NEDGES / 2; p += nw) {
        const int pu = __builtin_amdgcn_readfirstlane(p);
        const int e0 = 2 * pu;

        const int2 z01 = *(const int2*)(zp + e0);        // s_load_dwordx2
        const int zj0 = (z01.x >> 8) & 0xFF, zi0 = z01.x & 0xFF;
        const int zj1 = (z01.y >> 8) & 0xFF, zi1 = z01.y & 0xFF;

        const float* __restrict__ r0 = rbf + (size_t)e0 * NRAD;
        const float* __restrict__ r1 = r0 + NRAD;

        float2 a0 = *(const float2*)(T1 + zj0 * 128 + col);
        const float2 t0 = *(const float2*)(T2 + zi0 * 128 + col);
        float2 a1 = *(const float2*)(T1 + zj1 * 128 + col);
        const float2 t1 = *(const float2*)(T2 + zi1 * 128 + col);
        a0.x += t0.x; a0.y += t0.y;
        a1.x += t1.x; a1.y += t1.y;

        #pragma unroll
        for (int q = 0; q < NRAD; ++q) {
            const float s0 = r0[q];        // uniform -> SGPR operand
            const float s1 = r1[q];
            a0.x = fmaf(s0, wc[q].x, a0.x);
            a0.y = fmaf(s0, wc[q].y, a0.y);
            a1.x = fmaf(s1, wc[q].x, a1.x);
            a1.y = fmaf(s1, wc[q].y, a1.y);
        }

        float2 o0, o1;
        o0.x = a0.x * __builtin_amdgcn_rcpf(1.f + __expf(-a0.x));
        o0.y = a0.y * __builtin_amdgcn_rcpf(1.f + __expf(-a0.y));
        o1.x = a1.x * __builtin_amdgcn_rcpf(1.f + __expf(-a1.x));
        o1.y = a1.y * __builtin_amdgcn_rcpf(1.f + __expf(-a1.y));

        *(float2*)(out + (size_t)e0 * 128 + col)       = o0;
        *(float2*)(out + (size_t)(e0 + 1) * 128 + col) = o1;
    }
}

extern "C" void kernel_launch(void* const* d_in, const int* in_sizes, int n_in,
                              void* d_out, int out_size, void* d_ws, size_t ws_size,
                              hipStream_t stream) {
    const int*   x       = (const int*)d_in[0];
    const float* rbf     = (const float*)d_in[1];
    const int*   idx_i   = (const int*)d_in[2];
    const int*   idx_j   = (const int*)d_in[3];
    const float* embed_w = (const float*)d_in[4];
    const float* w_rbf   = (const float*)d_in[5];
    const float* w_edge  = (const float*)d_in[6];
    const float* b_edge  = (const float*)d_in[7];
    float* out = (float*)d_out;
    float* ws  = (float*)d_ws;
    int*   zp  = (int*)(ws + ZP_OFF);

    prep_kernel<<<MAXZ + NRAD, 128, 0, stream>>>(embed_w, w_rbf, w_edge, b_edge, ws);
    zp_kernel<<<NEDGES / 256, 256, 0, stream>>>(x, idx_i, idx_j, zp);
    edge_kernel<<<2048, 256, 0, stream>>>(rbf, zp, ws, out);
}

// Round 4
// 218.470 us; speedup vs baseline: 1.5728x; 1.4385x over previous
//
#include <hip/hip_runtime.h>
#include <cstddef>

#define NEDGES   800000
#define NRAD     32
#define MAXZ     100
#define T1_OFF   0
#define T2_OFF   (MAXZ * 128)                    // 12800 floats
#define WC_OFF   (2 * MAXZ * 128)                // 25600 floats
#define ZP_OFF   (2 * MAXZ * 128 + NRAD * 128)   // 29696 floats

typedef __attribute__((ext_vector_type(8))) short bf16x8;   // 8 bf16 = 4 VGPRs
typedef __attribute__((ext_vector_type(4))) float f32x4;

__device__ inline unsigned short f2bf(float f) {            // RTNE f32->bf16
    unsigned u = __float_as_uint(f);
    u += 0x7FFFu + ((u >> 16) & 1u);
    return (unsigned short)(u >> 16);
}
__device__ inline float bf2f(unsigned short h) {
    return __uint_as_float(((unsigned)h) << 16);
}

// ---------------------------------------------------------------------------
// Prep A: fold weights into tables (same as R3 — verified correct).
// ---------------------------------------------------------------------------
__global__ __launch_bounds__(128)
void prep_kernel(const float* __restrict__ embed_w,
                 const float* __restrict__ w_rbf,
                 const float* __restrict__ w_edge,
                 const float* __restrict__ b_edge,
                 float* __restrict__ ws) {
    const int d = threadIdx.x;
    const int b = blockIdx.x;
    if (b < MAXZ) {
        float a1 = b_edge[d];
        float a2 = 0.f;
        #pragma unroll 8
        for (int k = 0; k < 128; ++k) {
            const float e = embed_w[b * 128 + k];
            a1 = fmaf(e, w_edge[k * 128 + d], a1);
            a2 = fmaf(e, w_edge[(128 + k) * 128 + d], a2);
        }
        ws[T1_OFF + b * 128 + d] = a1;
        ws[T2_OFF + b * 128 + d] = a2;
    } else {
        const int q = b - MAXZ;
        float a = 0.f;
        #pragma unroll 8
        for (int m = 0; m < 128; ++m)
            a = fmaf(w_rbf[q * 128 + m], w_edge[(256 + m) * 128 + d], a);
        ws[WC_OFF + q * 128 + d] = a;
    }
}

// ---------------------------------------------------------------------------
// Prep B: zp[e] = (x[idx_j[e]] << 8) | x[idx_i[e]]
// ---------------------------------------------------------------------------
__global__ __launch_bounds__(256)
void zp_kernel(const int* __restrict__ x,
               const int* __restrict__ idx_i,
               const int* __restrict__ idx_j,
               int* __restrict__ zp) {
    const int e = blockIdx.x * 256 + threadIdx.x;
    zp[e] = (x[idx_j[e]] << 8) | x[idx_i[e]];
}

// ---------------------------------------------------------------------------
// Main (MFMA): per wave-iter, 16 edges x 128 cols.
//   A (16x32) = rbf tile, split bf16 hi+lo for precision.
//   B (32x16) x8 col-groups = Wc, register-resident bf16 frags, asm-pinned
//   so the allocator CANNOT rematerialize them (R2/R3 failure mode).
//   acc = A@B via 16 x mfma_f32_16x16x32_bf16 (no K-loop, no LDS).
//   Epilogue: + T1[zj] + T2[zi] gathers (quarter-wave 64B coalesced), silu.
// C layout (verified, m89): col = lane&15, row = (lane>>4)*4 + reg.
// ---------------------------------------------------------------------------
__global__ __launch_bounds__(256, 4)
void edge_kernel(const float* __restrict__ rbf,
                 const int* __restrict__ zp,
                 const float* __restrict__ ws,
                 float* __restrict__ out) {
    const int lane = threadIdx.x & 63;
    const int wid  = threadIdx.x >> 6;
    const int n16  = lane & 15;     // A row / B col / C col within group
    const int kh   = lane >> 4;     // K-block: k = kh*8 + j ; C rows kh*4+r

    const float* __restrict__ T1 = ws + T1_OFF;
    const float* __restrict__ T2 = ws + T2_OFF;
    const float* __restrict__ Wc = ws + WC_OFF;

    // Build 8 B-fragments: bhi[g][j] = bf16(Wc[kh*8+j][16g + n16])
    bf16x8 bhi[8];
    #pragma unroll
    for (int g = 0; g < 8; ++g) {
        #pragma unroll
        for (int j = 0; j < 8; ++j)
            bhi[g][j] = (short)f2bf(Wc[(kh * 8 + j) * 128 + 16 * g + n16]);
        asm volatile("" : "+v"(bhi[g]));    // opaque: cannot be re-loaded
    }

    const int nw = gridDim.x * 4;
    for (int grp = blockIdx.x * 4 + wid; grp < NEDGES / 16; grp += nw) {
        const int ebase = __builtin_amdgcn_readfirstlane(grp) * 16;

        // A fragment: rbf[ebase + n16][kh*8 .. kh*8+7], bf16 hi+lo split
        const float* arow = rbf + (size_t)(ebase + n16) * NRAD + kh * 8;
        const float4 a04 = *(const float4*)(arow);
        const float4 a44 = *(const float4*)(arow + 4);
        const float av[8] = {a04.x, a04.y, a04.z, a04.w,
                             a44.x, a44.y, a44.z, a44.w};
        bf16x8 ahi, alo;
        #pragma unroll
        for (int j = 0; j < 8; ++j) {
            const unsigned short h = f2bf(av[j]);
            ahi[j] = (short)h;
            alo[j] = (short)f2bf(av[j] - bf2f(h));
        }

        f32x4 acc[8];
        #pragma unroll
        for (int g = 0; g < 8; ++g) {
            acc[g] = (f32x4){0.f, 0.f, 0.f, 0.f};
            acc[g] = __builtin_amdgcn_mfma_f32_16x16x32_bf16(ahi, bhi[g], acc[g], 0, 0, 0);
            acc[g] = __builtin_amdgcn_mfma_f32_16x16x32_bf16(alo, bhi[g], acc[g], 0, 0, 0);
        }

        // zp for this lane's 4 C-rows: edges ebase + kh*4 + {0..3}
        const int4 zp4 = *(const int4*)(zp + ebase + kh * 4);
        const int zv[4] = {zp4.x, zp4.y, zp4.z, zp4.w};

        #pragma unroll
        for (int r = 0; r < 4; ++r) {
            const int zj = zv[r] >> 8;         // < 256, positive
            const int zi = zv[r] & 0xFF;
            const float* __restrict__ t1p = T1 + zj * 128 + n16;
            const float* __restrict__ t2p = T2 + zi * 128 + n16;
            float* __restrict__ op = out + (size_t)(ebase + kh * 4 + r) * 128 + n16;
            #pragma unroll
            for (int g = 0; g < 8; ++g) {
                const float v = acc[g][r] + t1p[16 * g] + t2p[16 * g];
                op[16 * g] = v * __builtin_amdgcn_rcpf(1.f + __expf(-v));
            }
        }
    }
}

extern "C" void kernel_launch(void* const* d_in, const int* in_sizes, int n_in,
                              void* d_out, int out_size, void* d_ws, size_t ws_size,
                              hipStream_t stream) {
    const int*   x       = (const int*)d_in[0];
    const float* rbf     = (const float*)d_in[1];
    const int*   idx_i   = (const int*)d_in[2];
    const int*   idx_j   = (const int*)d_in[3];
    const float* embed_w = (const float*)d_in[4];
    const float* w_rbf   = (const float*)d_in[5];
    const float* w_edge  = (const float*)d_in[6];
    const float* b_edge  = (const float*)d_in[7];
    float* out = (float*)d_out;
    float* ws  = (float*)d_ws;
    int*   zp  = (int*)(ws + ZP_OFF);

    prep_kernel<<<MAXZ + NRAD, 128, 0, stream>>>(embed_w, w_rbf, w_edge, b_edge, ws);
    zp_kernel<<<NEDGES / 256, 256, 0, stream>>>(x, idx_i, idx_j, zp);
    edge_kernel<<<1024, 256, 0, stream>>>(rbf, zp, ws, out);
}

// Round 5
// 185.852 us; speedup vs baseline: 1.8488x; 1.1755x over previous
//
#include <hip/hip_runtime.h>
#include <cstddef>

#define NEDGES   800000
#define NRAD     32
#define MAXZ     100
#define T1_OFF   0
#define T2_OFF   (MAXZ * 128)                    // 12800 floats
#define WC_OFF   (2 * MAXZ * 128)                // 25600 floats
#define FB_OFF   (2 * MAXZ * 128 + NRAD * 128)   // 29696 floats (B-frags, 8KB)
#define ZP_OFF   (FB_OFF + 2048)                 // 31744 floats, then 800000 ints

typedef __attribute__((ext_vector_type(8))) short bf16x8;   // 8 bf16 = 4 VGPRs
typedef __attribute__((ext_vector_type(4))) float f32x4;

__device__ inline unsigned short f2bf(float f) {            // RTNE f32->bf16
    unsigned u = __float_as_uint(f);
    u += 0x7FFFu + ((u >> 16) & 1u);
    return (unsigned short)(u >> 16);
}
__device__ inline float bf2f(unsigned short h) {
    return __uint_as_float(((unsigned)h) << 16);
}

// ---------------------------------------------------------------------------
// Prep A: fold weights into tables.
// ---------------------------------------------------------------------------
__global__ __launch_bounds__(128)
void prep_kernel(const float* __restrict__ embed_w,
                 const float* __restrict__ w_rbf,
                 const float* __restrict__ w_edge,
                 const float* __restrict__ b_edge,
                 float* __restrict__ ws) {
    const int d = threadIdx.x;
    const int b = blockIdx.x;
    if (b < MAXZ) {
        float a1 = b_edge[d];
        float a2 = 0.f;
        #pragma unroll 8
        for (int k = 0; k < 128; ++k) {
            const float e = embed_w[b * 128 + k];
            a1 = fmaf(e, w_edge[k * 128 + d], a1);
            a2 = fmaf(e, w_edge[(128 + k) * 128 + d], a2);
        }
        ws[T1_OFF + b * 128 + d] = a1;
        ws[T2_OFF + b * 128 + d] = a2;
    } else {
        const int q = b - MAXZ;
        float a = 0.f;
        #pragma unroll 8
        for (int m = 0; m < 128; ++m)
            a = fmaf(w_rbf[q * 128 + m], w_edge[(256 + m) * 128 + d], a);
        ws[WC_OFF + q * 128 + d] = a;
    }
}

// ---------------------------------------------------------------------------
// Prep B: (a) B-fragments of Wc in MFMA lane order, bf16:
//             FB[(g*64 + lane)*8 + j] = bf16(Wc[(lane>>4)*8 + j][16g + (lane&15)])
//         so edge_kernel loads them with 8 coalesced dwordx4.
//         (b) zp[e] = (x[idx_j[e]] << 8) | x[idx_i[e]].
// ---------------------------------------------------------------------------
__global__ __launch_bounds__(512)
void prep_b_kernel(const float* __restrict__ ws_in, float* __restrict__ ws) {
    const int tid  = threadIdx.x;
    const int g    = tid >> 6;
    const int lane = tid & 63;
    const int n16  = lane & 15;
    const int kh   = lane >> 4;
    unsigned short* FB = (unsigned short*)(ws + FB_OFF);
    #pragma unroll
    for (int j = 0; j < 8; ++j)
        FB[(g * 64 + lane) * 8 + j] =
            f2bf(ws_in[WC_OFF + (kh * 8 + j) * 128 + 16 * g + n16]);
}

__global__ __launch_bounds__(256)
void zp_kernel(const int* __restrict__ x,
               const int* __restrict__ idx_i,
               const int* __restrict__ idx_j,
               int* __restrict__ zp) {
    const int e = blockIdx.x * 256 + threadIdx.x;
    zp[e] = (x[idx_j[e]] << 8) | x[idx_i[e]];
}

// ---------------------------------------------------------------------------
// Main (MFMA, no loop): ONE 16-edge group per wave. 50000 waves total.
//   All latency hiding via TLP — no loop-carried dependence at all.
//   B-frags: 8 coalesced dwordx4 loads (precomputed order).
//   A: rbf 16x32 tile, bf16 hi+lo split (precision).
//   Epilogue: + T1[zj] + T2[zi] (quarter-wave 64B gathers), silu, store.
// C layout: col = 16g + (lane&15), row = (lane>>4)*4 + reg.
// ---------------------------------------------------------------------------
__global__ __launch_bounds__(256, 4)
void edge_kernel(const float* __restrict__ rbf,
                 const int* __restrict__ zp,
                 const float* __restrict__ ws,
                 float* __restrict__ out) {
    const int lane = threadIdx.x & 63;
    const int wid  = threadIdx.x >> 6;
    const int n16  = lane & 15;
    const int kh   = lane >> 4;
    const int grp  = blockIdx.x * 4 + wid;       // wave-uniform
    const int ebase = grp * 16;

    const float* __restrict__ T1 = ws + T1_OFF;
    const float* __restrict__ T2 = ws + T2_OFF;
    const bf16x8* __restrict__ FB = (const bf16x8*)(ws + FB_OFF);

    // B fragments: 8 coalesced 16B loads
    bf16x8 bhi[8];
    #pragma unroll
    for (int g = 0; g < 8; ++g)
        bhi[g] = FB[g * 64 + lane];

    // A fragment: rbf[ebase + n16][kh*8 .. kh*8+7], bf16 hi+lo split
    const float* arow = rbf + (size_t)(ebase + n16) * NRAD + kh * 8;
    const float4 a04 = *(const float4*)(arow);
    const float4 a44 = *(const float4*)(arow + 4);

    // zp for this lane's 4 C-rows: edges ebase + kh*4 + {0..3}
    const int4 zp4 = *(const int4*)(zp + ebase + kh * 4);

    const float av[8] = {a04.x, a04.y, a04.z, a04.w,
                         a44.x, a44.y, a44.z, a44.w};
    bf16x8 ahi, alo;
    #pragma unroll
    for (int j = 0; j < 8; ++j) {
        const unsigned short h = f2bf(av[j]);
        ahi[j] = (short)h;
        alo[j] = (short)f2bf(av[j] - bf2f(h));
    }

    f32x4 acc[8];
    #pragma unroll
    for (int g = 0; g < 8; ++g) {
        acc[g] = (f32x4){0.f, 0.f, 0.f, 0.f};
        acc[g] = __builtin_amdgcn_mfma_f32_16x16x32_bf16(ahi, bhi[g], acc[g], 0, 0, 0);
        acc[g] = __builtin_amdgcn_mfma_f32_16x16x32_bf16(alo, bhi[g], acc[g], 0, 0, 0);
    }

    const int zv[4] = {zp4.x, zp4.y, zp4.z, zp4.w};
    #pragma unroll
    for (int r = 0; r < 4; ++r) {
        const int zj = zv[r] >> 8;
        const int zi = zv[r] & 0xFF;
        const float* __restrict__ t1p = T1 + zj * 128 + n16;
        const float* __restrict__ t2p = T2 + zi * 128 + n16;
        float* __restrict__ op = out + (size_t)(ebase + kh * 4 + r) * 128 + n16;
        #pragma unroll
        for (int g = 0; g < 8; ++g) {
            const float v = acc[g][r] + t1p[16 * g] + t2p[16 * g];
            op[16 * g] = v * __builtin_amdgcn_rcpf(1.f + __expf(-v));
        }
    }
}

extern "C" void kernel_launch(void* const* d_in, const int* in_sizes, int n_in,
                              void* d_out, int out_size, void* d_ws, size_t ws_size,
                              hipStream_t stream) {
    const int*   x       = (const int*)d_in[0];
    const float* rbf     = (const float*)d_in[1];
    const int*   idx_i   = (const int*)d_in[2];
    const int*   idx_j   = (const int*)d_in[3];
    const float* embed_w = (const float*)d_in[4];
    const float* w_rbf   = (const float*)d_in[5];
    const float* w_edge  = (const float*)d_in[6];
    const float* b_edge  = (const float*)d_in[7];
    float* out = (float*)d_out;
    float* ws  = (float*)d_ws;
    int*   zp  = (int*)(ws + ZP_OFF);

    prep_kernel<<<MAXZ + NRAD, 128, 0, stream>>>(embed_w, w_rbf, w_edge, b_edge, ws);
    prep_b_kernel<<<1, 512, 0, stream>>>(ws, ws);
    zp_kernel<<<NEDGES / 256, 256, 0, stream>>>(x, idx_i, idx_j, zp);
    edge_kernel<<<NEDGES / 64, 256, 0, stream>>>(rbf, zp, ws, out);
}